// Round 5
// baseline (304.691 us; speedup 1.0000x reference)
//
#include <hip/hip_runtime.h>

// Problem constants (fixed shapes)
#define BB 8192      // batch
#define DZ 1024
#define DS 64
#define DH 4096
#define KEXT (DH + DS)   // 4160: K of GEMM2 = [H | s]

typedef float floatx16 __attribute__((ext_vector_type(16)));
typedef __bf16 bf16x8 __attribute__((ext_vector_type(8)));
typedef __attribute__((address_space(1))) void* as1_void_ptr;
typedef __attribute__((address_space(3))) void* as3_void_ptr;

// s_waitcnt immediates (gfx9 encoding: vmcnt[3:0]|[15:14], expcnt[6:4], lgkmcnt[11:8])
#define WAIT_VM4   3956   // vmcnt(4),  lgkm/exp unconstrained
#define WAIT_VM0   3952   // vmcnt(0),  lgkm/exp unconstrained
#define WAIT_LGKM0 49279  // lgkmcnt(0), vmcnt/exp unconstrained

__device__ __forceinline__ void async_copy16(const void* g, void* l) {
    // global -> LDS direct copy, 16B/lane; per-lane GLOBAL address,
    // wave-uniform LDS base + lane*16 dest.
    __builtin_amdgcn_global_load_lds((as1_void_ptr)g, (as3_void_ptr)l, 16, 0, 0);
}

// ---------------- merged prep kernel ----------------
__global__ void prep_all(const float* __restrict__ z, const float* __restrict__ W1,
                         const float* __restrict__ W2, const float* __restrict__ C,
                         const float* __restrict__ s,
                         __bf16* __restrict__ zb, __bf16* __restrict__ W1b,
                         __bf16* __restrict__ B2b, __bf16* __restrict__ Hb) {
    const int b = blockIdx.x, t = threadIdx.x;
    if (b < 8192) {
        int i = b * 256 + t;
        float4 v = ((const float4*)z)[i];
        __bf16* o = zb + (size_t)i * 4;
        o[0] = (__bf16)v.x; o[1] = (__bf16)v.y; o[2] = (__bf16)v.z; o[3] = (__bf16)v.w;
    } else if (b < 12288) {
        int i = (b - 8192) * 256 + t;
        float4 v = ((const float4*)W1)[i];
        __bf16* o = W1b + (size_t)i * 4;
        o[0] = (__bf16)v.x; o[1] = (__bf16)v.y; o[2] = (__bf16)v.z; o[3] = (__bf16)v.w;
    } else if (b < 13312) {
        int j = b - 12288;
        for (int h = t; h < KEXT; h += 256) {
            float v = (h < DH) ? W2[(size_t)j * DH + h] : C[(size_t)j * DS + (h - DH)];
            B2b[(size_t)j * KEXT + h] = (__bf16)v;
        }
    } else {
        int i = (b - 13312) * 256 + t;        // 0 .. 8192*64-1
        int r = i >> 6, k = i & 63;
        Hb[(size_t)r * KEXT + DH + k] = (__bf16)s[i];
    }
}

// ---------------- GEMM structure (both kernels) ----------------
// 128x128 tile, BK=32, double-buffered LDS (2 x (8KB A + 8KB B) = 32 KB).
// Raw s_barrier + manual vmcnt(4): next tile's 4 global_load_lds stay in
// flight across the entire MFMA phase (no compiler vmcnt(0) drain).
// MFMA: 32x32x16 bf16; wave w computes 64x64 as 2x2 tiles of 32x32.
// LDS tile layout: row-major 128x32, row stride 64B, with XOR chunk swizzle:
//   16B chunk c of row r stored at chunk position (c ^ (r&3)).
// Swizzle is applied on the staging GLOBAL address (lane permutation within
// each 64B row), so global_load_lds's contiguous-lane rule is preserved and
// the 32x32 frag reads hit all 8 bank quads (8-cyc floor, no conflicts).

// A-frag (per 32x32 MFMA, K=16): row = lane&31, k = (lane>>5)*8 + j.
// C/D layout (verified m74/m101): col = lane&31, row = (reg&3)+8*(reg>>2)+4*(lane>>5).

#define GEMM_PIPELINE_BODY(KITER_, ldA_, ldB_)                                          \
    const int tid = threadIdx.x;                                                        \
    const int wave = tid >> 6, lane = tid & 63;                                         \
    const int wm = wave >> 1, wn = wave & 1;                                            \
    const int row0 = blockIdx.x * 128;                                                  \
    const int col0 = blockIdx.y * 128;                                                  \
    const int srow = tid >> 2;                       /* staging row 0..63 */            \
    const int schk = (tid & 3) ^ (srow & 3);         /* swizzled global chunk */        \
    const __bf16* pA = Ag + (size_t)(row0 + srow) * ldA_ + schk * 8;                    \
    const __bf16* pB = Bg + (size_t)(col0 + srow) * ldB_ + schk * 8;                    \
    const int mA = lane & 31, hA = lane >> 5;                                           \
    floatx16 acc[2][2];                                                                 \
    acc[0][0] = (floatx16)0.0f; acc[0][1] = (floatx16)0.0f;                             \
    acc[1][0] = (floatx16)0.0f; acc[1][1] = (floatx16)0.0f;                             \
    {   /* prologue: issue tile 0 into buffer 0 */                                      \
        __bf16* lA = As + wave * 512;                                                   \
        __bf16* lB = Bs + wave * 512;                                                   \
        async_copy16(pA,                    lA);                                        \
        async_copy16(pA + (size_t)64*ldA_,  lA + 2048);                                 \
        async_copy16(pB,                    lB);                                        \
        async_copy16(pB + (size_t)64*ldB_,  lB + 2048);                                 \
    }                                                                                   \
    for (int kt = 0; kt < KITER_; ++kt) {                                               \
        const int p = kt & 1;                                                           \
        if (kt + 1 < KITER_) {                                                          \
            const __bf16* ak = pA + (kt + 1) * 32;                                      \
            const __bf16* bk = pB + (kt + 1) * 32;                                      \
            __bf16* lA = As + (p ^ 1) * 4096 + wave * 512;                              \
            __bf16* lB = Bs + (p ^ 1) * 4096 + wave * 512;                              \
            async_copy16(ak,                    lA);                                    \
            async_copy16(ak + (size_t)64*ldA_,  lA + 2048);                             \
            async_copy16(bk,                    lB);                                    \
            async_copy16(bk + (size_t)64*ldB_,  lB + 2048);                             \
            __builtin_amdgcn_s_waitcnt(WAIT_VM4);                                       \
        } else {                                                                        \
            __builtin_amdgcn_s_waitcnt(WAIT_VM0);                                       \
        }                                                                               \
        __builtin_amdgcn_s_barrier();                                                   \
        const __bf16* Ab = As + p * 4096;                                               \
        const __bf16* Bb = Bs + p * 4096;                                               \
        _Pragma("unroll")                                                               \
        for (int ks = 0; ks < 2; ++ks) {                                                \
            bf16x8 af[2], bf[2];                                                        \
            _Pragma("unroll")                                                           \
            for (int i = 0; i < 2; ++i) {                                               \
                int r = wm * 64 + i * 32 + mA;                                          \
                int chunk = (ks * 2 + hA) ^ (mA & 3);                                   \
                af[i] = *(const bf16x8*)(Ab + r * 32 + chunk * 8);                      \
            }                                                                           \
            _Pragma("unroll")                                                           \
            for (int j = 0; j < 2; ++j) {                                               \
                int r = wn * 64 + j * 32 + mA;                                          \
                int chunk = (ks * 2 + hA) ^ (mA & 3);                                   \
                bf[j] = *(const bf16x8*)(Bb + r * 32 + chunk * 8);                      \
            }                                                                           \
            _Pragma("unroll")                                                           \
            for (int i = 0; i < 2; ++i)                                                 \
                _Pragma("unroll")                                                       \
                for (int j = 0; j < 2; ++j)                                             \
                    acc[i][j] = __builtin_amdgcn_mfma_f32_32x32x16_bf16(                \
                        af[i], bf[j], acc[i][j], 0, 0, 0);                              \
        }                                                                               \
        __builtin_amdgcn_s_waitcnt(WAIT_LGKM0);                                         \
        __builtin_amdgcn_s_barrier();                                                   \
    }

// ---------------- GEMM1: Hb[:, :4096] = relu(zb @ W1b^T + h1) ----------------
__global__ __launch_bounds__(256) void gemm1_relu(
    const __bf16* __restrict__ Ag, const __bf16* __restrict__ Bg,
    const float* __restrict__ h1, __bf16* __restrict__ Hb)
{
    __shared__ __align__(16) __bf16 As[2 * 128 * 32];   // 16 KB
    __shared__ __align__(16) __bf16 Bs[2 * 128 * 32];   // 16 KB

    GEMM_PIPELINE_BODY(32, DZ, DZ)

    // epilogue: 32x32 C/D layout
#pragma unroll
    for (int i = 0; i < 2; ++i) {
#pragma unroll
        for (int j = 0; j < 2; ++j) {
            const int cbase = col0 + wn * 64 + j * 32 + mA;
            const float bias = h1[cbase];
#pragma unroll
            for (int rg = 0; rg < 16; ++rg) {
                const int r = row0 + wm * 64 + i * 32 + (rg & 3) + 8 * (rg >> 2) + 4 * hA;
                float v = acc[i][j][rg] + bias;
                v = v > 0.0f ? v : 0.0f;
                Hb[(size_t)r * KEXT + cbase] = (__bf16)v;
            }
        }
    }
}

// ---------------- GEMM2: out = Hb @ B2b^T + A*zb + h2 ----------------
__global__ __launch_bounds__(256) void gemm2_out(
    const __bf16* __restrict__ Ag, const __bf16* __restrict__ Bg,
    const float* __restrict__ Adiag, const float* __restrict__ h2,
    const __bf16* __restrict__ zb, float* __restrict__ out)
{
    __shared__ __align__(16) __bf16 As[2 * 128 * 32];
    __shared__ __align__(16) __bf16 Bs[2 * 128 * 32];

    GEMM_PIPELINE_BODY(130, KEXT, KEXT)

#pragma unroll
    for (int i = 0; i < 2; ++i) {
#pragma unroll
        for (int j = 0; j < 2; ++j) {
            const int c = col0 + wn * 64 + j * 32 + mA;
            const float aj = Adiag[c];
            const float hj = h2[c];
#pragma unroll
            for (int rg = 0; rg < 16; ++rg) {
                const int r = row0 + wm * 64 + i * 32 + (rg & 3) + 8 * (rg >> 2) + 4 * hA;
                out[(size_t)r * DZ + c] =
                    acc[i][j][rg] + aj * (float)zb[(size_t)r * DZ + c] + hj;
            }
        }
    }
}

// ---------------- launch ----------------

extern "C" void kernel_launch(void* const* d_in, const int* in_sizes, int n_in,
                              void* d_out, int out_size, void* d_ws, size_t ws_size,
                              hipStream_t stream) {
    const float* z  = (const float*)d_in[0];   // [8192,1024]
    const float* s  = (const float*)d_in[1];   // [8192,64]
    const float* A  = (const float*)d_in[2];   // [1024]
    const float* W1 = (const float*)d_in[3];   // [4096,1024]
    const float* W2 = (const float*)d_in[4];   // [1024,4096]
    const float* h1 = (const float*)d_in[5];   // [4096]
    const float* h2 = (const float*)d_in[6];   // [1024]
    const float* C  = (const float*)d_in[7];   // [1024,64]
    float* out = (float*)d_out;

    // workspace layout (bytes): Hb | zb | W1b | B2b  ~= 102 MB total
    char* ws = (char*)d_ws;
    size_t offHb  = 0;
    size_t offZb  = offHb  + (size_t)BB * KEXT * 2;
    size_t offW1b = offZb  + (size_t)BB * DZ * 2;
    size_t offB2b = offW1b + (size_t)DH * DZ * 2;
    __bf16* Hb  = (__bf16*)(ws + offHb);    // [8192 x 4160]
    __bf16* zb  = (__bf16*)(ws + offZb);    // [8192 x 1024]
    __bf16* W1b = (__bf16*)(ws + offW1b);   // [4096 x 1024]
    __bf16* B2b = (__bf16*)(ws + offB2b);   // [1024 x 4160] = [W2 | C]

    prep_all<<<15360, 256, 0, stream>>>(z, W1, W2, C, s, zb, W1b, B2b, Hb);
    gemm1_relu<<<dim3(BB / 128, DH / 128), 256, 0, stream>>>(zb, W1b, h1, Hb);
    gemm2_out<<<dim3(BB / 128, DZ / 128), 256, 0, stream>>>(Hb, B2b, A, h2, zb, out);
}

// Round 6
// 294.101 us; speedup vs baseline: 1.0360x; 1.0360x over previous
//
#include <hip/hip_runtime.h>

// Problem constants (fixed shapes)
#define BB 8192      // batch
#define DZ 1024
#define DS 64
#define DH 4096
#define KEXT (DH + DS)   // 4160: K of GEMM2 = [H | s]

typedef float floatx4 __attribute__((ext_vector_type(4)));
typedef __bf16 bf16x8 __attribute__((ext_vector_type(8)));
typedef __attribute__((address_space(1))) void* as1_void_ptr;
typedef __attribute__((address_space(3))) void* as3_void_ptr;

// s_waitcnt immediates (gfx9: vmcnt[3:0]|[15:14], expcnt[6:4], lgkmcnt[11:8])
#define WAIT_VM0   3952   // vmcnt(0), lgkm/exp unconstrained
#define WAIT_VM4   3956   // vmcnt(4)
#define WAIT_VM8   3960   // vmcnt(8)
#define WAIT_LGKM0 49279  // lgkmcnt(0), vm/exp unconstrained

__device__ __forceinline__ void async_copy16(const void* g, void* l) {
    // global -> LDS direct copy, 16B/lane; per-lane GLOBAL address,
    // wave-uniform LDS base + lane*16 dest.
    __builtin_amdgcn_global_load_lds((as1_void_ptr)g, (as3_void_ptr)l, 16, 0, 0);
}

// ---------------- merged prep kernel ----------------
__global__ void prep_all(const float* __restrict__ z, const float* __restrict__ W1,
                         const float* __restrict__ W2, const float* __restrict__ C,
                         const float* __restrict__ s,
                         __bf16* __restrict__ zb, __bf16* __restrict__ W1b,
                         __bf16* __restrict__ B2b, __bf16* __restrict__ Hb) {
    const int b = blockIdx.x, t = threadIdx.x;
    if (b < 8192) {
        int i = b * 256 + t;
        float4 v = ((const float4*)z)[i];
        __bf16* o = zb + (size_t)i * 4;
        o[0] = (__bf16)v.x; o[1] = (__bf16)v.y; o[2] = (__bf16)v.z; o[3] = (__bf16)v.w;
    } else if (b < 12288) {
        int i = (b - 8192) * 256 + t;
        float4 v = ((const float4*)W1)[i];
        __bf16* o = W1b + (size_t)i * 4;
        o[0] = (__bf16)v.x; o[1] = (__bf16)v.y; o[2] = (__bf16)v.z; o[3] = (__bf16)v.w;
    } else if (b < 13312) {
        int j = b - 12288;
        for (int h = t; h < KEXT; h += 256) {
            float v = (h < DH) ? W2[(size_t)j * DH + h] : C[(size_t)j * DS + (h - DH)];
            B2b[(size_t)j * KEXT + h] = (__bf16)v;
        }
    } else {
        int i = (b - 13312) * 256 + t;        // 0 .. 8192*64-1
        int r = i >> 6, k = i & 63;
        Hb[(size_t)r * KEXT + DH + k] = (__bf16)s[i];
    }
}

// Shared structure notes:
//  - 128x128 block tile, 4 waves, wave (wm,wn) owns a 64x64 quadrant computed
//    as 4x4 grid of 16x16x32 bf16 MFMA (the verified m97 fragment layout:
//    frag row = lane&15, k-chunk = lane>>4; C/D col = lane&15,
//    row = (lane>>4)*4 + reg). 2-way LDS bank aliasing only (free, m136).
//  - LDS tiles row-major 128x32 (64B row stride), staged via global_load_lds:
//    thread t loads global row row0 + (t>>2), 16B chunk (t&3); wave w's lanes
//    land at slab base + w*512 + lane*8 elems.
//  - Explicit double-buffer + raw s_barrier + manual vmcnt(N): next tile's
//    copies are issued BEFORE waiting on the current tile, so the global->LDS
//    transfer overlaps the whole MFMA phase (no vmcnt(0) drain per iter).

// ---------------- GEMM1: Hb[:, :4096] = relu(zb @ W1b^T + h1) ----------------
// A = zb [8192 x 1024] K-major, B = W1b [4096 x 1024] K-major. BK=32, dbuf.
__global__ __launch_bounds__(256) void gemm1_relu(
    const __bf16* __restrict__ Ag, const __bf16* __restrict__ Bg,
    const float* __restrict__ h1, __bf16* __restrict__ Hb)
{
    constexpr int ldA = DZ, ldB = DZ, KITER = DZ / 32;
    __shared__ __align__(16) __bf16 As[2 * 128 * 32];   // dbuf: 16 KB
    __shared__ __align__(16) __bf16 Bs[2 * 128 * 32];   // dbuf: 16 KB

    const int tid = threadIdx.x;
    const int wave = tid >> 6, lane = tid & 63;
    const int wm = wave >> 1, wn = wave & 1;
    const int row0 = blockIdx.x * 128;
    const int col0 = blockIdx.y * 128;

    const __bf16* pA = Ag + (size_t)(row0 + (tid >> 2)) * ldA + (tid & 3) * 8;
    const __bf16* pB = Bg + (size_t)(col0 + (tid >> 2)) * ldB + (tid & 3) * 8;

    const __bf16* Afrag = As + (wm * 64 + (lane & 15)) * 32 + (lane >> 4) * 8;
    const __bf16* Bfrag = Bs + (wn * 64 + (lane & 15)) * 32 + (lane >> 4) * 8;

    floatx4 acc[4][4];
#pragma unroll
    for (int i = 0; i < 4; ++i)
#pragma unroll
        for (int j = 0; j < 4; ++j) acc[i][j] = (floatx4)0.0f;

    {   // prologue: tile 0 -> buffer 0
        __bf16* lA = As + wave * 512;
        __bf16* lB = Bs + wave * 512;
        async_copy16(pA,                        lA);
        async_copy16(pA + (size_t)64 * ldA,     lA + 2048);
        async_copy16(pB,                        lB);
        async_copy16(pB + (size_t)64 * ldB,     lB + 2048);
    }

    for (int kt = 0; kt < KITER; ++kt) {
        const int p = kt & 1;
        if (kt + 1 < KITER) {
            const __bf16* ak = pA + (kt + 1) * 32;
            const __bf16* bk = pB + (kt + 1) * 32;
            __bf16* lA = As + (p ^ 1) * 4096 + wave * 512;
            __bf16* lB = Bs + (p ^ 1) * 4096 + wave * 512;
            async_copy16(ak,                    lA);
            async_copy16(ak + (size_t)64 * ldA, lA + 2048);
            async_copy16(bk,                    lB);
            async_copy16(bk + (size_t)64 * ldB, lB + 2048);
            __builtin_amdgcn_s_waitcnt(WAIT_VM4);   // prior tile's 4 done; new 4 in flight
        } else {
            __builtin_amdgcn_s_waitcnt(WAIT_VM0);
        }
        __builtin_amdgcn_s_barrier();

        const __bf16* Ab = Afrag + p * 4096;
        const __bf16* Bb = Bfrag + p * 4096;
        bf16x8 af[4], bfr[4];
#pragma unroll
        for (int i = 0; i < 4; ++i) af[i] = *(const bf16x8*)(Ab + i * 16 * 32);
#pragma unroll
        for (int j = 0; j < 4; ++j) bfr[j] = *(const bf16x8*)(Bb + j * 16 * 32);
#pragma unroll
        for (int i = 0; i < 4; ++i)
#pragma unroll
            for (int j = 0; j < 4; ++j)
                acc[i][j] = __builtin_amdgcn_mfma_f32_16x16x32_bf16(af[i], bfr[j], acc[i][j], 0, 0, 0);

        __builtin_amdgcn_s_waitcnt(WAIT_LGKM0);     // ds_reads of buf p complete
        __builtin_amdgcn_s_barrier();               // safe to refill buf p next iter
    }

    // epilogue: C/D layout col = lane&15, row = (lane>>4)*4 + reg
    const int r0 = row0 + wm * 64 + (lane >> 4) * 4;
    const int c0 = col0 + wn * 64 + (lane & 15);
#pragma unroll
    for (int i = 0; i < 4; ++i) {
#pragma unroll
        for (int j = 0; j < 4; ++j) {
            int c = c0 + j * 16;
            float bias = h1[c];
#pragma unroll
            for (int rg = 0; rg < 4; ++rg) {
                int r = r0 + i * 16 + rg;
                float v = acc[i][j][rg] + bias;
                v = v > 0.0f ? v : 0.0f;
                Hb[(size_t)r * KEXT + c] = (__bf16)v;
            }
        }
    }
}

// ---------------- GEMM2: out = Hb @ B2b^T + A*zb + h2 ----------------
// A = Hb [8192 x 4160] K-major, B = B2b [1024 x 4160] K-major. BK=64, dbuf.
// 64 KB LDS: gemm2 is grid-capped at 2 blocks/CU anyway, so this is free.
__global__ __launch_bounds__(256) void gemm2_out(
    const __bf16* __restrict__ Ag, const __bf16* __restrict__ Bg,
    const float* __restrict__ Adiag, const float* __restrict__ h2,
    const __bf16* __restrict__ zb, float* __restrict__ out)
{
    constexpr int ldA = KEXT, ldB = KEXT, KITER = KEXT / 64;
    __shared__ __align__(16) __bf16 As[2 * 2 * 128 * 32];   // dbuf x 2 panels: 32 KB
    __shared__ __align__(16) __bf16 Bs[2 * 2 * 128 * 32];   // 32 KB

    const int tid = threadIdx.x;
    const int wave = tid >> 6, lane = tid & 63;
    const int wm = wave >> 1, wn = wave & 1;
    const int row0 = blockIdx.x * 128;
    const int col0 = blockIdx.y * 128;

    const __bf16* pA = Ag + (size_t)(row0 + (tid >> 2)) * ldA + (tid & 3) * 8;
    const __bf16* pB = Bg + (size_t)(col0 + (tid >> 2)) * ldB + (tid & 3) * 8;

    const __bf16* Afrag = As + (wm * 64 + (lane & 15)) * 32 + (lane >> 4) * 8;
    const __bf16* Bfrag = Bs + (wn * 64 + (lane & 15)) * 32 + (lane >> 4) * 8;

    floatx4 acc[4][4];
#pragma unroll
    for (int i = 0; i < 4; ++i)
#pragma unroll
        for (int j = 0; j < 4; ++j) acc[i][j] = (floatx4)0.0f;

    {   // prologue: tile 0 -> buffer 0 (panels: K-cols [0,32) then [32,64))
        __bf16* lA = As + wave * 512;
        __bf16* lB = Bs + wave * 512;
        async_copy16(pA,                             lA);
        async_copy16(pA + (size_t)64 * ldA,          lA + 2048);
        async_copy16(pA + 32,                        lA + 4096);
        async_copy16(pA + (size_t)64 * ldA + 32,     lA + 4096 + 2048);
        async_copy16(pB,                             lB);
        async_copy16(pB + (size_t)64 * ldB,          lB + 2048);
        async_copy16(pB + 32,                        lB + 4096);
        async_copy16(pB + (size_t)64 * ldB + 32,     lB + 4096 + 2048);
    }

    for (int kt = 0; kt < KITER; ++kt) {
        const int p = kt & 1;
        if (kt + 1 < KITER) {
            const __bf16* ak = pA + (kt + 1) * 64;
            const __bf16* bk = pB + (kt + 1) * 64;
            __bf16* lA = As + (p ^ 1) * 8192 + wave * 512;
            __bf16* lB = Bs + (p ^ 1) * 8192 + wave * 512;
            async_copy16(ak,                         lA);
            async_copy16(ak + (size_t)64 * ldA,      lA + 2048);
            async_copy16(ak + 32,                    lA + 4096);
            async_copy16(ak + (size_t)64 * ldA + 32, lA + 4096 + 2048);
            async_copy16(bk,                         lB);
            async_copy16(bk + (size_t)64 * ldB,      lB + 2048);
            async_copy16(bk + 32,                    lB + 4096);
            async_copy16(bk + (size_t)64 * ldB + 32, lB + 4096 + 2048);
            __builtin_amdgcn_s_waitcnt(WAIT_VM8);   // prior tile's 8 done; new 8 in flight
        } else {
            __builtin_amdgcn_s_waitcnt(WAIT_VM0);
        }
        __builtin_amdgcn_s_barrier();

#pragma unroll
        for (int ks = 0; ks < 2; ++ks) {
            const __bf16* Ab = Afrag + p * 8192 + ks * 4096;
            const __bf16* Bb = Bfrag + p * 8192 + ks * 4096;
            bf16x8 af[4], bfr[4];
#pragma unroll
            for (int i = 0; i < 4; ++i) af[i] = *(const bf16x8*)(Ab + i * 16 * 32);
#pragma unroll
            for (int j = 0; j < 4; ++j) bfr[j] = *(const bf16x8*)(Bb + j * 16 * 32);
#pragma unroll
            for (int i = 0; i < 4; ++i)
#pragma unroll
                for (int j = 0; j < 4; ++j)
                    acc[i][j] = __builtin_amdgcn_mfma_f32_16x16x32_bf16(af[i], bfr[j], acc[i][j], 0, 0, 0);
        }

        __builtin_amdgcn_s_waitcnt(WAIT_LGKM0);
        __builtin_amdgcn_s_barrier();
    }

    const int r0 = row0 + wm * 64 + (lane >> 4) * 4;
    const int c0 = col0 + wn * 64 + (lane & 15);
#pragma unroll
    for (int i = 0; i < 4; ++i) {
#pragma unroll
        for (int j = 0; j < 4; ++j) {
            const int c = c0 + j * 16;
            const float aj = Adiag[c];
            const float hj = h2[c];
#pragma unroll
            for (int rg = 0; rg < 4; ++rg) {
                const int r = r0 + i * 16 + rg;
                out[(size_t)r * DZ + c] =
                    acc[i][j][rg] + aj * (float)zb[(size_t)r * DZ + c] + hj;
            }
        }
    }
}

// ---------------- launch ----------------

extern "C" void kernel_launch(void* const* d_in, const int* in_sizes, int n_in,
                              void* d_out, int out_size, void* d_ws, size_t ws_size,
                              hipStream_t stream) {
    const float* z  = (const float*)d_in[0];   // [8192,1024]
    const float* s  = (const float*)d_in[1];   // [8192,64]
    const float* A  = (const float*)d_in[2];   // [1024]
    const float* W1 = (const float*)d_in[3];   // [4096,1024]
    const float* W2 = (const float*)d_in[4];   // [1024,4096]
    const float* h1 = (const float*)d_in[5];   // [4096]
    const float* h2 = (const float*)d_in[6];   // [1024]
    const float* C  = (const float*)d_in[7];   // [1024,64]
    float* out = (float*)d_out;

    // workspace layout (bytes): Hb | zb | W1b | B2b  ~= 102 MB total
    char* ws = (char*)d_ws;
    size_t offHb  = 0;
    size_t offZb  = offHb  + (size_t)BB * KEXT * 2;
    size_t offW1b = offZb  + (size_t)BB * DZ * 2;
    size_t offB2b = offW1b + (size_t)DH * DZ * 2;
    __bf16* Hb  = (__bf16*)(ws + offHb);    // [8192 x 4160]
    __bf16* zb  = (__bf16*)(ws + offZb);    // [8192 x 1024]
    __bf16* W1b = (__bf16*)(ws + offW1b);   // [4096 x 1024]
    __bf16* B2b = (__bf16*)(ws + offB2b);   // [1024 x 4160] = [W2 | C]

    prep_all<<<15360, 256, 0, stream>>>(z, W1, W2, C, s, zb, W1b, B2b, Hb);
    gemm1_relu<<<dim3(BB / 128, DH / 128), 256, 0, stream>>>(zb, W1b, h1, Hb);
    gemm2_out<<<dim3(BB / 128, DZ / 128), 256, 0, stream>>>(Hb, B2b, A, h2, zb, out);
}

// Round 7
// 259.616 us; speedup vs baseline: 1.1736x; 1.1328x over previous
//
#include <hip/hip_runtime.h>

// Problem constants (fixed shapes)
#define BB 8192      // batch
#define DZ 1024
#define DS 64
#define DH 4096
#define KEXT (DH + DS)   // 4160: K of GEMM2 = [H | s]

typedef float floatx4 __attribute__((ext_vector_type(4)));
typedef __bf16 bf16x8 __attribute__((ext_vector_type(8)));
typedef __bf16 bf16x4 __attribute__((ext_vector_type(4)));
typedef __attribute__((address_space(1))) void* as1_void_ptr;
typedef __attribute__((address_space(3))) void* as3_void_ptr;

// s_waitcnt immediates (gfx9: vmcnt[3:0] bits0-3 + [5:4] bits15:14,
// expcnt bits6:4, lgkmcnt bits11:8). lgkm=15,exp=7 "unconstrained" base = 3952.
#define WAIT_VM0   3952   // vmcnt(0)
#define WAIT_VM6   3958   // vmcnt(6)
#define WAIT_LGKM0 49279  // lgkmcnt(0), vm/exp unconstrained

__device__ __forceinline__ void async_copy16(const void* g, void* l) {
    // global -> LDS direct copy, 16B/lane; per-lane GLOBAL address,
    // wave-uniform LDS base + lane*16 dest.
    __builtin_amdgcn_global_load_lds((as1_void_ptr)g, (as3_void_ptr)l, 16, 0, 0);
}

__device__ __forceinline__ bf16x4 cvt4(float4 v) {
    bf16x4 o = { (__bf16)v.x, (__bf16)v.y, (__bf16)v.z, (__bf16)v.w };
    return o;
}

// ---------------- merged prep kernel (all stores 8B) ----------------
// blocks [0,8192): z->zb; [8192,12288): W1->W1b; [12288,13312): B2b=[W2|C];
// [13312,13824): s -> Hb[:, 4096:4160]
__global__ void prep_all(const float* __restrict__ z, const float* __restrict__ W1,
                         const float* __restrict__ W2, const float* __restrict__ C,
                         const float* __restrict__ s,
                         __bf16* __restrict__ zb, __bf16* __restrict__ W1b,
                         __bf16* __restrict__ B2b, __bf16* __restrict__ Hb) {
    const int b = blockIdx.x, t = threadIdx.x;
    if (b < 8192) {
        int i = b * 256 + t;
        *(bf16x4*)(zb + (size_t)i * 4) = cvt4(((const float4*)z)[i]);
    } else if (b < 12288) {
        int i = (b - 8192) * 256 + t;
        *(bf16x4*)(W1b + (size_t)i * 4) = cvt4(((const float4*)W1)[i]);
    } else if (b < 13312) {
        int j = b - 12288;
        const float* wrow = W2 + (size_t)j * DH;
        const float* crow = C + (size_t)j * DS;
        __bf16* orow = B2b + (size_t)j * KEXT;
        for (int c = t; c < 520; c += 256) {   // 520 chunks of 8 elems
            int h = c * 8;
            const float* src = (h < DH) ? (wrow + h) : (crow + (h - DH));
            *(bf16x4*)(orow + h)     = cvt4(*(const float4*)(src));
            *(bf16x4*)(orow + h + 4) = cvt4(*(const float4*)(src + 4));
        }
    } else {
        int i = (b - 13312) * 256 + t;        // 0 .. 131071 chunks of 4
        int r = i >> 4, k = (i & 15) * 4;
        float4 v = *(const float4*)(s + (size_t)r * DS + k);
        *(bf16x4*)(Hb + (size_t)r * KEXT + DH + k) = cvt4(v);
    }
}

// Shared structure: 256x128 block tile, 512 threads = 8 waves; wave w
// (wm = w>>1 in 0..3, wn = w&1) owns 64x64 via 4x4 grid of 16x16x32 MFMA
// (verified m97 fragment layout; 2-way LDS aliasing = free).
// LDS per operand: K-panels of [rows x 32] row-major (64B row stride).
// A tile 256x64 = 2 panels of 256x32 (16 KB total... 32 KB), B tile 128x64 =
// 2 panels of 128x32 (16 KB). Staging: thread t loads global row
// base + (t>>2), 16B chunk (t&3); wave w's lanes -> slab base + w*512 elems.
// 6 global_load_lds per K-tile (A rows 0-127/128-255 x 2 panels, B x 2 panels).

// ---------------- GEMM1: Hb[:, :4096] = relu(zb @ W1b^T + h1) ----------------
// A = zb [8192 x 1024] K-major, B = W1b [4096 x 1024] K-major. BK=64,
// single-buffer (r4-proven sync), 48 KB LDS, 2 blocks/CU.
__global__ __launch_bounds__(512, 4) void gemm1_relu(
    const __bf16* __restrict__ Ag, const __bf16* __restrict__ Bg,
    const float* __restrict__ h1, __bf16* __restrict__ Hb)
{
    constexpr int ldA = DZ, ldB = DZ, KITER = DZ / 64;
    __shared__ __align__(16) __bf16 As[256 * 64];   // 32 KB (2 panels of 256x32)
    __shared__ __align__(16) __bf16 Bs[128 * 64];   // 16 KB (2 panels of 128x32)

    const int tid = threadIdx.x;
    const int wave = tid >> 6, lane = tid & 63;
    const int wm = wave >> 1, wn = wave & 1;
    const int row0 = blockIdx.x * 256;
    const int col0 = blockIdx.y * 128;

    const __bf16* pA = Ag + (size_t)(row0 + (tid >> 2)) * ldA + (tid & 3) * 8;
    const __bf16* pB = Bg + (size_t)(col0 + ((tid >> 2) & 127)) * ldB + (tid & 3) * 8;
    __bf16* lA = As + wave * 512;   // + lane*8 implicit (8 waves cover 128 rows)
    __bf16* lB = Bs + wave * 512;

    const __bf16* Afrag = As + (wm * 64 + (lane & 15)) * 32 + (lane >> 4) * 8;
    const __bf16* Bfrag = Bs + (wn * 64 + (lane & 15)) * 32 + (lane >> 4) * 8;

    floatx4 acc[4][4];
#pragma unroll
    for (int i = 0; i < 4; ++i)
#pragma unroll
        for (int j = 0; j < 4; ++j) acc[i][j] = (floatx4)0.0f;

    for (int kt = 0; kt < KITER; ++kt) {
        const __bf16* ak = pA + kt * 64;
        const __bf16* bk = pB + kt * 64;
        // A: rows 0-127 / 128-255, panels k+0 / k+32
        async_copy16(ak,                           lA);
        async_copy16(ak + (size_t)128 * ldA,       lA + 4096);
        async_copy16(ak + 32,                      lA + 8192);
        async_copy16(ak + (size_t)128 * ldA + 32,  lA + 8192 + 4096);
        // B: 128 rows, panels k+0 / k+32
        async_copy16(bk,                           lB);
        async_copy16(bk + 32,                      lB + 4096);
        __builtin_amdgcn_s_waitcnt(0);
        __syncthreads();

#pragma unroll
        for (int ks = 0; ks < 2; ++ks) {
            bf16x8 af[4], bfr[4];
#pragma unroll
            for (int i = 0; i < 4; ++i) af[i] = *(const bf16x8*)(Afrag + ks * 8192 + i * 16 * 32);
#pragma unroll
            for (int j = 0; j < 4; ++j) bfr[j] = *(const bf16x8*)(Bfrag + ks * 4096 + j * 16 * 32);
#pragma unroll
            for (int i = 0; i < 4; ++i)
#pragma unroll
                for (int j = 0; j < 4; ++j)
                    acc[i][j] = __builtin_amdgcn_mfma_f32_16x16x32_bf16(af[i], bfr[j], acc[i][j], 0, 0, 0);
        }
        __syncthreads();
    }

    // epilogue: C/D layout col = lane&15, row = (lane>>4)*4 + reg
    const int r0 = row0 + wm * 64 + (lane >> 4) * 4;
    const int c0 = col0 + wn * 64 + (lane & 15);
#pragma unroll
    for (int i = 0; i < 4; ++i) {
#pragma unroll
        for (int j = 0; j < 4; ++j) {
            int c = c0 + j * 16;
            float bias = h1[c];
#pragma unroll
            for (int rg = 0; rg < 4; ++rg) {
                int r = r0 + i * 16 + rg;
                float v = acc[i][j][rg] + bias;
                v = v > 0.0f ? v : 0.0f;
                Hb[(size_t)r * KEXT + c] = (__bf16)v;
            }
        }
    }
}

// ---------------- GEMM2: out = Hb @ B2b^T + A*zb + h2 ----------------
// A = Hb [8192 x 4160] K-major, B = B2b [1024 x 4160] K-major. BK=64.
// Grid = 32x8 = 256 blocks = exactly 1/CU -> explicit dbuf raw-barrier
// pipeline (96 KB LDS, free at 1 block/CU) so staging overlaps MFMA.
__global__ __launch_bounds__(512, 2) void gemm2_out(
    const __bf16* __restrict__ Ag, const __bf16* __restrict__ Bg,
    const float* __restrict__ Adiag, const float* __restrict__ h2,
    const __bf16* __restrict__ zb, float* __restrict__ out)
{
    constexpr int ldA = KEXT, ldB = KEXT, KITER = KEXT / 64;
    __shared__ __align__(16) __bf16 As[2 * 256 * 64];   // 64 KB dbuf
    __shared__ __align__(16) __bf16 Bs[2 * 128 * 64];   // 32 KB dbuf

    const int tid = threadIdx.x;
    const int wave = tid >> 6, lane = tid & 63;
    const int wm = wave >> 1, wn = wave & 1;
    const int row0 = blockIdx.x * 256;
    const int col0 = blockIdx.y * 128;

    const __bf16* pA = Ag + (size_t)(row0 + (tid >> 2)) * ldA + (tid & 3) * 8;
    const __bf16* pB = Bg + (size_t)(col0 + ((tid >> 2) & 127)) * ldB + (tid & 3) * 8;

    const __bf16* Afrag = As + (wm * 64 + (lane & 15)) * 32 + (lane >> 4) * 8;
    const __bf16* Bfrag = Bs + (wn * 64 + (lane & 15)) * 32 + (lane >> 4) * 8;

    floatx4 acc[4][4];
#pragma unroll
    for (int i = 0; i < 4; ++i)
#pragma unroll
        for (int j = 0; j < 4; ++j) acc[i][j] = (floatx4)0.0f;

    // issue tile kt into buffer q (6 copies)
    auto issue = [&](int kt, int q) {
        const __bf16* ak = pA + kt * 64;
        const __bf16* bk = pB + kt * 64;
        __bf16* lA = As + q * 16384 + wave * 512;
        __bf16* lB = Bs + q * 8192  + wave * 512;
        async_copy16(ak,                           lA);
        async_copy16(ak + (size_t)128 * ldA,       lA + 4096);
        async_copy16(ak + 32,                      lA + 8192);
        async_copy16(ak + (size_t)128 * ldA + 32,  lA + 8192 + 4096);
        async_copy16(bk,                           lB);
        async_copy16(bk + 32,                      lB + 4096);
    };

    issue(0, 0);   // prologue

    for (int kt = 0; kt < KITER; ++kt) {
        const int p = kt & 1;
        if (kt + 1 < KITER) {
            issue(kt + 1, p ^ 1);
            __builtin_amdgcn_s_waitcnt(WAIT_VM6);   // prior tile's 6 done; 6 in flight
        } else {
            __builtin_amdgcn_s_waitcnt(WAIT_VM0);
        }
        __builtin_amdgcn_s_barrier();

#pragma unroll
        for (int ks = 0; ks < 2; ++ks) {
            const __bf16* Ab = Afrag + p * 16384 + ks * 8192;
            const __bf16* Bb = Bfrag + p * 8192  + ks * 4096;
            bf16x8 af[4], bfr[4];
#pragma unroll
            for (int i = 0; i < 4; ++i) af[i] = *(const bf16x8*)(Ab + i * 16 * 32);
#pragma unroll
            for (int j = 0; j < 4; ++j) bfr[j] = *(const bf16x8*)(Bb + j * 16 * 32);
#pragma unroll
            for (int i = 0; i < 4; ++i)
#pragma unroll
                for (int j = 0; j < 4; ++j)
                    acc[i][j] = __builtin_amdgcn_mfma_f32_16x16x32_bf16(af[i], bfr[j], acc[i][j], 0, 0, 0);
        }

        __builtin_amdgcn_s_waitcnt(WAIT_LGKM0);     // reads of buf p done
        __builtin_amdgcn_s_barrier();               // safe to refill buf p
    }

    const int r0 = row0 + wm * 64 + (lane >> 4) * 4;
    const int c0 = col0 + wn * 64 + (lane & 15);
#pragma unroll
    for (int i = 0; i < 4; ++i) {
#pragma unroll
        for (int j = 0; j < 4; ++j) {
            const int c = c0 + j * 16;
            const float aj = Adiag[c];
            const float hj = h2[c];
#pragma unroll
            for (int rg = 0; rg < 4; ++rg) {
                const int r = r0 + i * 16 + rg;
                out[(size_t)r * DZ + c] =
                    acc[i][j][rg] + aj * (float)zb[(size_t)r * DZ + c] + hj;
            }
        }
    }
}

// ---------------- launch ----------------

extern "C" void kernel_launch(void* const* d_in, const int* in_sizes, int n_in,
                              void* d_out, int out_size, void* d_ws, size_t ws_size,
                              hipStream_t stream) {
    const float* z  = (const float*)d_in[0];   // [8192,1024]
    const float* s  = (const float*)d_in[1];   // [8192,64]
    const float* A  = (const float*)d_in[2];   // [1024]
    const float* W1 = (const float*)d_in[3];   // [4096,1024]
    const float* W2 = (const float*)d_in[4];   // [1024,4096]
    const float* h1 = (const float*)d_in[5];   // [4096]
    const float* h2 = (const float*)d_in[6];   // [1024]
    const float* C  = (const float*)d_in[7];   // [1024,64]
    float* out = (float*)d_out;

    // workspace layout (bytes): Hb | zb | W1b | B2b  ~= 102 MB total
    char* ws = (char*)d_ws;
    size_t offHb  = 0;
    size_t offZb  = offHb  + (size_t)BB * KEXT * 2;
    size_t offW1b = offZb  + (size_t)BB * DZ * 2;
    size_t offB2b = offW1b + (size_t)DH * DZ * 2;
    __bf16* Hb  = (__bf16*)(ws + offHb);    // [8192 x 4160]
    __bf16* zb  = (__bf16*)(ws + offZb);    // [8192 x 1024]
    __bf16* W1b = (__bf16*)(ws + offW1b);   // [4096 x 1024]
    __bf16* B2b = (__bf16*)(ws + offB2b);   // [1024 x 4160] = [W2 | C]

    prep_all<<<13824, 256, 0, stream>>>(z, W1, W2, C, s, zb, W1b, B2b, Hb);
    gemm1_relu<<<dim3(BB / 256, DH / 128), 512, 0, stream>>>(zb, W1b, h1, Hb);
    gemm2_out<<<dim3(BB / 256, DZ / 128), 512, 0, stream>>>(Hb, B2b, A, h2, zb, out);
}